// Round 3
// baseline (560.718 us; speedup 1.0000x reference)
//
#include <hip/hip_runtime.h>
#include <hip/hip_bf16.h>

typedef __bf16 bf16;
typedef __bf16 bf16x4 __attribute__((ext_vector_type(4)));
typedef __bf16 bf16x8 __attribute__((ext_vector_type(8)));
typedef float  f32x4  __attribute__((ext_vector_type(4)));

#define H_DIM 1024
#define NHEAD 16
#define HD    64

__device__ __forceinline__ void gload_lds16(const bf16* g, bf16* l) {
    __builtin_amdgcn_global_load_lds((const __attribute__((address_space(1))) void*)g,
                                     (__attribute__((address_space(3))) void*)l, 16, 0, 0);
}

// ---------------- weight fp32 [K][N] -> bf16 [N][K] (transpose+convert) ----------------
__global__ __launch_bounds__(256) void wconv_kernel(const float* __restrict__ W,
                                                    bf16* __restrict__ Wt,
                                                    int K, int N) {
    __shared__ float tile[64][65];
    const int n0 = blockIdx.x * 64, k0 = blockIdx.y * 64;
    const int t = threadIdx.x;
#pragma unroll
    for (int p = 0; p < 4; ++p) {
        int lin = p * 1024 + t * 4;
        int r = lin >> 6, c = lin & 63;
        f32x4 v = *(const f32x4*)(W + (size_t)(k0 + r) * N + n0 + c);
        tile[r][c]     = v[0];
        tile[r][c + 1] = v[1];
        tile[r][c + 2] = v[2];
        tile[r][c + 3] = v[3];
    }
    __syncthreads();
#pragma unroll
    for (int p = 0; p < 4; ++p) {
        int lin = p * 1024 + t * 4;
        int rn = lin >> 6, ck = lin & 63;
        bf16x4 o;
#pragma unroll
        for (int j = 0; j < 4; ++j) o[j] = (bf16)tile[ck + j][rn];
        *(bf16x4*)(Wt + (size_t)(n0 + rn) * K + k0 + ck) = o;
    }
}

// ---------------- layernorm (fp32 in, bf16 out), one row per block ----------------
__global__ __launch_bounds__(256) void ln_kernel(const float* __restrict__ in, float inScale,
                                                 const float* __restrict__ g,
                                                 const float* __restrict__ b,
                                                 bf16* __restrict__ out) {
    const int row = blockIdx.x, t = threadIdx.x;
    const float* p = in + (size_t)row * H_DIM;
    f32x4 v = *(const f32x4*)(p + t * 4);
    v *= inScale;
    float s1 = v[0] + v[1] + v[2] + v[3];
    float s2 = v[0] * v[0] + v[1] * v[1] + v[2] * v[2] + v[3] * v[3];
#pragma unroll
    for (int m = 1; m < 64; m <<= 1) {
        s1 += __shfl_xor(s1, m);
        s2 += __shfl_xor(s2, m);
    }
    __shared__ float red[8];
    const int wave = t >> 6;
    if ((t & 63) == 0) { red[wave * 2] = s1; red[wave * 2 + 1] = s2; }
    __syncthreads();
    s1 = red[0] + red[2] + red[4] + red[6];
    s2 = red[1] + red[3] + red[5] + red[7];
    float mean = s1 * (1.0f / H_DIM);
    float var  = s2 * (1.0f / H_DIM) - mean * mean;
    float inv  = rsqrtf(var + 1e-5f);
    f32x4 gg = *(const f32x4*)(g + t * 4);
    f32x4 bb = *(const f32x4*)(b + t * 4);
    bf16x4 o;
#pragma unroll
    for (int j = 0; j < 4; ++j) o[j] = (bf16)((v[j] - mean) * inv * gg[j] + bb[j]);
    *(bf16x4*)(out + (size_t)row * H_DIM + t * 4) = o;
}

// ---------------- fp32 -> bf16 with scale ----------------
__global__ __launch_bounds__(256) void cvt_scale_kernel(const float* __restrict__ in,
                                                        bf16* __restrict__ out,
                                                        float s, int n4) {
    int i = blockIdx.x * 256 + threadIdx.x;
    if (i < n4) {
        f32x4 v = *(const f32x4*)(in + (size_t)i * 4);
        bf16x4 o;
#pragma unroll
        for (int j = 0; j < 4; ++j) o[j] = (bf16)(v[j] * s);
        *(bf16x4*)(out + (size_t)i * 4) = o;
    }
}

// ---------------- GEMM (m97 structure): C[M,N]=A[M,K]*Bt[N,K]^T + bias, fused epilogues ----
// TRANS_OUT: write bf16 output in [b][h][d][s] layout (for attention V), s = row & (S-1)
template <bool OUT_BF16, bool GELU_EPI, bool HAS_RES, bool TRANS_OUT>
__global__ __launch_bounds__(256) void gemm_kernel(const bf16* __restrict__ A,
                                                   const bf16* __restrict__ Bt,
                                                   const float* __restrict__ bias,
                                                   const float* __restrict__ res,
                                                   void* __restrict__ outp,
                                                   int M, int N, int K,
                                                   float resScale, float outScale,
                                                   int slog2) {
    __shared__ bf16 Al[128][64];   // linear: global_load_lds dest must be contiguous
    __shared__ bf16 Bl[128][64];
    const int m0 = blockIdx.y * 128, n0 = blockIdx.x * 128;
    const int tid = threadIdx.x;
    const int wave = tid >> 6, lane = tid & 63, lr = lane & 15, lhi = lane >> 4;
    const int wr = wave >> 1, wc = wave & 1;
    const int sr = lane >> 3, sc = (lane & 7) * 8;   // staging coords within wave chunk
    f32x4 acc[4][4] = {};
    for (int k0 = 0; k0 < K; k0 += 64) {
        __syncthreads();
#pragma unroll
        for (int p = 0; p < 4; ++p) {
            const int r = p * 32 + wave * 8 + sr;
            bf16* lA = &Al[0][0] + p * 2048 + wave * 512;   // wave-uniform base
            bf16* lB = &Bl[0][0] + p * 2048 + wave * 512;
            gload_lds16(A  + (size_t)(m0 + r) * K + k0 + sc, lA);
            gload_lds16(Bt + (size_t)(n0 + r) * K + k0 + sc, lB);
        }
        __syncthreads();   // drains vmcnt(0) before barrier
#pragma unroll
        for (int kk = 0; kk < 2; ++kk) {
            bf16x8 af[4], bfr[4];
#pragma unroll
            for (int i = 0; i < 4; ++i) {
                af[i]  = *(const bf16x8*)&Al[wr * 64 + i * 16 + lr][kk * 32 + lhi * 8];
                bfr[i] = *(const bf16x8*)&Bl[wc * 64 + i * 16 + lr][kk * 32 + lhi * 8];
            }
#pragma unroll
            for (int i = 0; i < 4; ++i)
#pragma unroll
                for (int j = 0; j < 4; ++j)
                    acc[i][j] = __builtin_amdgcn_mfma_f32_16x16x32_bf16(af[i], bfr[j], acc[i][j], 0, 0, 0);
        }
    }
#pragma unroll
    for (int i = 0; i < 4; ++i) {
#pragma unroll
        for (int j = 0; j < 4; ++j) {
            const int col = n0 + wc * 64 + j * 16 + lr;
            const float bv = bias[col];
            if (TRANS_OUT) {
                const int row0 = m0 + wr * 64 + i * 16 + lhi * 4;
                const int S = 1 << slog2;
                const int bI = row0 >> slog2, s0 = row0 & (S - 1);
                const int hI = col >> 6, dI = col & 63;
                bf16x4 o;
#pragma unroll
                for (int r = 0; r < 4; ++r) o[r] = (bf16)(acc[i][j][r] + bv);
                *(bf16x4*)((bf16*)outp + ((size_t)((bI * NHEAD + hI) * HD + dI)) * S + s0) = o;
            } else {
#pragma unroll
                for (int r = 0; r < 4; ++r) {
                    const int row = m0 + wr * 64 + i * 16 + lhi * 4 + r;
                    const size_t idx = (size_t)row * N + col;
                    float v = acc[i][j][r] + bv;
                    if (HAS_RES) v += res[idx] * resScale;
                    if (GELU_EPI) v = 0.5f * v * (1.0f + erff(v * 0.70710678118654752f));
                    v *= outScale;
                    if (OUT_BF16) ((bf16*)outp)[idx] = (bf16)v;
                    else          ((float*)outp)[idx] = v;
                }
            }
        }
    }
}

// ---------------- flash attention v2: 128 q-rows/block, pre-transposed V ----------------
// Vt_g layout: [b][h][d][k]  (produced by the V-projection GEMM epilogue)
__global__ __launch_bounds__(256) void attn_kernel(const bf16* __restrict__ Qb,
                                                   const bf16* __restrict__ Kb,
                                                   const bf16* __restrict__ Vt_g,
                                                   bf16* __restrict__ Ob,
                                                   int SQ, int SK, float scale) {
    __shared__ bf16 Kl[64][72];    // [key][chan], +8 pad -> 2-way alias only (free)
    __shared__ bf16 Vl[64][72];    // [d][key]
    __shared__ bf16 Pl[4][32][72]; // per-wave P relayout
    const int b = blockIdx.x >> 4, h = blockIdx.x & 15;
    const int q0 = blockIdx.y * 128;
    const int tid = threadIdx.x, wave = tid >> 6, lane = tid & 63;
    const int lr = lane & 15, lhi = lane >> 4;
    const size_t bh = (size_t)blockIdx.x;

    bf16x8 qf[2][2];
#pragma unroll
    for (int qi = 0; qi < 2; ++qi) {
        const bf16* qp = Qb + ((size_t)b * SQ + q0 + wave * 32 + qi * 16 + lr) * H_DIM + h * HD;
        qf[qi][0] = *(const bf16x8*)(qp + lhi * 8);
        qf[qi][1] = *(const bf16x8*)(qp + 32 + lhi * 8);
    }
    float mrun[2][4], lrun[2][4];
    f32x4 o[2][4] = {};
#pragma unroll
    for (int qi = 0; qi < 2; ++qi)
#pragma unroll
        for (int r = 0; r < 4; ++r) { mrun[qi][r] = -1e30f; lrun[qi][r] = 0.f; }

    for (int kb = 0; kb < SK; kb += 64) {
        __syncthreads();
#pragma unroll
        for (int p = 0; p < 2; ++p) {
            int lin = (p * 256 + tid) * 8;
            int r = lin >> 6, c = lin & 63;
            *(bf16x8*)&Kl[r][c] = *(const bf16x8*)(Kb + ((size_t)b * SK + kb + r) * H_DIM + h * HD + c);
            *(bf16x8*)&Vl[r][c] = *(const bf16x8*)(Vt_g + (bh * 64 + r) * SK + kb + c);
        }
        __syncthreads();

        // S[32q x 64k] per wave (2 q-frags)
        f32x4 s[2][4];
#pragma unroll
        for (int nf = 0; nf < 4; ++nf) {
            bf16x8 kf0 = *(const bf16x8*)&Kl[nf * 16 + lr][lhi * 8];
            bf16x8 kf1 = *(const bf16x8*)&Kl[nf * 16 + lr][32 + lhi * 8];
#pragma unroll
            for (int qi = 0; qi < 2; ++qi) {
                f32x4 sc = {};
                sc = __builtin_amdgcn_mfma_f32_16x16x32_bf16(qf[qi][0], kf0, sc, 0, 0, 0);
                sc = __builtin_amdgcn_mfma_f32_16x16x32_bf16(qf[qi][1], kf1, sc, 0, 0, 0);
                s[qi][nf] = sc * scale;
            }
        }
        // online softmax (reduce over k: lanes lr; rows = lhi*4+r)
#pragma unroll
        for (int qi = 0; qi < 2; ++qi) {
            float tm[4];
#pragma unroll
            for (int r = 0; r < 4; ++r)
                tm[r] = fmaxf(fmaxf(s[qi][0][r], s[qi][1][r]), fmaxf(s[qi][2][r], s[qi][3][r]));
#pragma unroll
            for (int m = 1; m < 16; m <<= 1)
#pragma unroll
                for (int r = 0; r < 4; ++r) tm[r] = fmaxf(tm[r], __shfl_xor(tm[r], m));
            float alpha[4];
#pragma unroll
            for (int r = 0; r < 4; ++r) {
                float mn = fmaxf(mrun[qi][r], tm[r]);
                alpha[r] = __expf(mrun[qi][r] - mn);
                mrun[qi][r] = mn;
            }
            float rs[4] = {0.f, 0.f, 0.f, 0.f};
#pragma unroll
            for (int nf = 0; nf < 4; ++nf)
#pragma unroll
                for (int r = 0; r < 4; ++r) {
                    float pv = __expf(s[qi][nf][r] - mrun[qi][r]);
                    s[qi][nf][r] = pv;
                    rs[r] += pv;
                }
#pragma unroll
            for (int m = 1; m < 16; m <<= 1)
#pragma unroll
                for (int r = 0; r < 4; ++r) rs[r] += __shfl_xor(rs[r], m);
#pragma unroll
            for (int r = 0; r < 4; ++r) lrun[qi][r] = lrun[qi][r] * alpha[r] + rs[r];
#pragma unroll
            for (int df = 0; df < 4; ++df)
#pragma unroll
                for (int r = 0; r < 4; ++r) o[qi][df][r] *= alpha[r];
#pragma unroll
            for (int nf = 0; nf < 4; ++nf)
#pragma unroll
                for (int r = 0; r < 4; ++r)
                    Pl[wave][qi * 16 + lhi * 4 + r][nf * 16 + lr] = (bf16)s[qi][nf][r];
        }
        // Pl is wave-private: intra-wave LDS drain, no barrier needed
        asm volatile("s_waitcnt lgkmcnt(0)" ::: "memory");
        // PV
#pragma unroll
        for (int kk = 0; kk < 2; ++kk) {
            bf16x8 pf[2];
#pragma unroll
            for (int qi = 0; qi < 2; ++qi)
                pf[qi] = *(const bf16x8*)&Pl[wave][qi * 16 + lr][kk * 32 + lhi * 8];
#pragma unroll
            for (int df = 0; df < 4; ++df) {
                bf16x8 vf = *(const bf16x8*)&Vl[df * 16 + lr][kk * 32 + lhi * 8];
#pragma unroll
                for (int qi = 0; qi < 2; ++qi)
                    o[qi][df] = __builtin_amdgcn_mfma_f32_16x16x32_bf16(pf[qi], vf, o[qi][df], 0, 0, 0);
            }
        }
    }
#pragma unroll
    for (int qi = 0; qi < 2; ++qi)
#pragma unroll
        for (int df = 0; df < 4; ++df)
#pragma unroll
            for (int r = 0; r < 4; ++r) {
                const int qrow = q0 + wave * 32 + qi * 16 + lhi * 4 + r;
                Ob[((size_t)b * SQ + qrow) * H_DIM + h * HD + df * 16 + lr] =
                    (bf16)(o[qi][df][r] / lrun[qi][r]);
            }
}

extern "C" void kernel_launch(void* const* d_in, const int* in_sizes, int n_in,
                              void* d_out, int out_size, void* d_ws, size_t ws_size,
                              hipStream_t stream) {
    const float* x    = (const float*)d_in[0];
    const float* img  = (const float*)d_in[1];
    const float* W_sq = (const float*)d_in[2];   const float* b_sq = (const float*)d_in[3];
    const float* W_sk = (const float*)d_in[4];   const float* b_sk = (const float*)d_in[5];
    const float* W_sv = (const float*)d_in[6];   const float* b_sv = (const float*)d_in[7];
    const float* W_so = (const float*)d_in[8];   const float* b_so = (const float*)d_in[9];
    const float* W_cq = (const float*)d_in[10];  const float* b_cq = (const float*)d_in[11];
    const float* W_ck = (const float*)d_in[12];  const float* b_ck = (const float*)d_in[13];
    const float* W_cv = (const float*)d_in[14];  const float* b_cv = (const float*)d_in[15];
    const float* W_co = (const float*)d_in[16];  const float* b_co = (const float*)d_in[17];
    const float* W_f1 = (const float*)d_in[18];  const float* b_f1 = (const float*)d_in[19];
    const float* W_f2 = (const float*)d_in[20];  const float* b_f2 = (const float*)d_in[21];
    const float* g1 = (const float*)d_in[22];    const float* bb1 = (const float*)d_in[23];
    const float* g2 = (const float*)d_in[24];    const float* bb2 = (const float*)d_in[25];
    const float* g3 = (const float*)d_in[26];    const float* bb3 = (const float*)d_in[27];

    char* ws = (char*)d_ws;
    const size_t MB = 1ull << 20;
    bf16* WT   = (bf16*)ws;
    bf16* w_sq = WT + 0 * (1u << 20);
    bf16* w_sk = WT + 1 * (1u << 20);
    bf16* w_sv = WT + 2 * (1u << 20);
    bf16* w_so = WT + 3 * (1u << 20);
    bf16* w_cq = WT + 4 * (1u << 20);
    bf16* w_ck = WT + 5 * (1u << 20);
    bf16* w_cv = WT + 6 * (1u << 20);
    bf16* w_co = WT + 7 * (1u << 20);
    bf16* w_f1 = WT + 8 * (1u << 20);       // [4096][1024]
    bf16* w_f2 = WT + 12 * (1u << 20);      // [1024][4096]
    float* XR  = (float*)(ws + 32 * MB);    // residual spine fp32 [4096,1024]
    bf16* NX   = (bf16*)(ws + 48 * MB);     // ln-out / attn-out bf16
    bf16* Qb   = (bf16*)(ws + 56 * MB);
    bf16* Kb   = (bf16*)(ws + 64 * MB);
    bf16* Vt   = (bf16*)(ws + 72 * MB);     // [b][h][d][k]
    bf16* FF   = (bf16*)(ws + 56 * MB);     // reuse Q/K/V region: [4096,4096] bf16
    bf16* IMGB = (bf16*)(ws + 88 * MB);     // [512,1024] bf16

    const dim3 blk(256);

    wconv_kernel<<<dim3(16, 16), blk, 0, stream>>>(W_sq, w_sq, 1024, 1024);
    wconv_kernel<<<dim3(16, 16), blk, 0, stream>>>(W_sk, w_sk, 1024, 1024);
    wconv_kernel<<<dim3(16, 16), blk, 0, stream>>>(W_sv, w_sv, 1024, 1024);
    wconv_kernel<<<dim3(16, 16), blk, 0, stream>>>(W_so, w_so, 1024, 1024);
    wconv_kernel<<<dim3(16, 16), blk, 0, stream>>>(W_cq, w_cq, 1024, 1024);
    wconv_kernel<<<dim3(16, 16), blk, 0, stream>>>(W_ck, w_ck, 1024, 1024);
    wconv_kernel<<<dim3(16, 16), blk, 0, stream>>>(W_cv, w_cv, 1024, 1024);
    wconv_kernel<<<dim3(16, 16), blk, 0, stream>>>(W_co, w_co, 1024, 1024);
    wconv_kernel<<<dim3(64, 16), blk, 0, stream>>>(W_f1, w_f1, 1024, 4096);
    wconv_kernel<<<dim3(16, 64), blk, 0, stream>>>(W_f2, w_f2, 4096, 1024);

    // ---- self attention ----
    ln_kernel<<<4096, blk, 0, stream>>>(x, 0.1f, g1, bb1, NX);
    gemm_kernel<true, false, false, false><<<dim3(8, 32), blk, 0, stream>>>(NX, w_sq, b_sq, nullptr, Qb, 4096, 1024, 1024, 0.f, 1.f, 0);
    gemm_kernel<true, false, false, false><<<dim3(8, 32), blk, 0, stream>>>(NX, w_sk, b_sk, nullptr, Kb, 4096, 1024, 1024, 0.f, 1.f, 0);
    gemm_kernel<true, false, false, true ><<<dim3(8, 32), blk, 0, stream>>>(NX, w_sv, b_sv, nullptr, Vt, 4096, 1024, 1024, 0.f, 1.f, 11);
    attn_kernel<<<dim3(32, 16), blk, 0, stream>>>(Qb, Kb, Vt, NX, 2048, 2048, 0.125f);
    gemm_kernel<false, false, true, false><<<dim3(8, 32), blk, 0, stream>>>(NX, w_so, b_so, x, XR, 4096, 1024, 1024, 0.1f, 1.f, 0);

    // ---- cross attention ----
    ln_kernel<<<4096, blk, 0, stream>>>(XR, 1.f, g2, bb2, NX);
    gemm_kernel<true, false, false, false><<<dim3(8, 32), blk, 0, stream>>>(NX, w_cq, b_cq, nullptr, Qb, 4096, 1024, 1024, 0.f, 1.f, 0);
    cvt_scale_kernel<<<dim3(512), blk, 0, stream>>>(img, IMGB, 0.1f, 131072);
    gemm_kernel<true, false, false, false><<<dim3(8, 4), blk, 0, stream>>>(IMGB, w_ck, b_ck, nullptr, Kb, 512, 1024, 1024, 0.f, 1.f, 0);
    gemm_kernel<true, false, false, true ><<<dim3(8, 4), blk, 0, stream>>>(IMGB, w_cv, b_cv, nullptr, Vt, 512, 1024, 1024, 0.f, 1.f, 8);
    attn_kernel<<<dim3(32, 16), blk, 0, stream>>>(Qb, Kb, Vt, NX, 2048, 256, 0.125f);
    gemm_kernel<false, false, true, false><<<dim3(8, 32), blk, 0, stream>>>(NX, w_co, b_co, XR, XR, 4096, 1024, 1024, 1.f, 1.f, 0);

    // ---- feed forward ----
    ln_kernel<<<4096, blk, 0, stream>>>(XR, 1.f, g3, bb3, NX);
    gemm_kernel<true, true, false, false><<<dim3(32, 32), blk, 0, stream>>>(NX, w_f1, b_f1, nullptr, FF, 4096, 4096, 1024, 0.f, 1.f, 0);
    gemm_kernel<false, false, true, false><<<dim3(8, 32), blk, 0, stream>>>(FF, w_f2, b_f2, XR, d_out, 4096, 1024, 4096, 1.f, 10.f, 0);
}

// Round 4
// 439.974 us; speedup vs baseline: 1.2744x; 1.2744x over previous
//
#include <hip/hip_runtime.h>
#include <hip/hip_bf16.h>

typedef __bf16 bf16;
typedef __bf16 bf16x4 __attribute__((ext_vector_type(4)));
typedef __bf16 bf16x8 __attribute__((ext_vector_type(8)));
typedef float  f32x4  __attribute__((ext_vector_type(4)));

#define H_DIM 1024
#define NHEAD 16
#define HD    64
// SCALE * log2(e), folded into Q-projection epilogue; attn softmax runs in base-2
#define QSCL 0.18033688011112042f

__device__ __forceinline__ void gload_lds16(const bf16* g, bf16* l) {
    __builtin_amdgcn_global_load_lds((const __attribute__((address_space(1))) void*)g,
                                     (__attribute__((address_space(3))) void*)l, 16, 0, 0);
}

// ---------------- weight fp32 [K][N] -> bf16 [N][K] (transpose+convert) ----------------
__global__ __launch_bounds__(256) void wconv_kernel(const float* __restrict__ W,
                                                    bf16* __restrict__ Wt,
                                                    int K, int N) {
    __shared__ float tile[64][65];
    const int n0 = blockIdx.x * 64, k0 = blockIdx.y * 64;
    const int t = threadIdx.x;
#pragma unroll
    for (int p = 0; p < 4; ++p) {
        int lin = p * 1024 + t * 4;
        int r = lin >> 6, c = lin & 63;
        f32x4 v = *(const f32x4*)(W + (size_t)(k0 + r) * N + n0 + c);
        tile[r][c]     = v[0];
        tile[r][c + 1] = v[1];
        tile[r][c + 2] = v[2];
        tile[r][c + 3] = v[3];
    }
    __syncthreads();
#pragma unroll
    for (int p = 0; p < 4; ++p) {
        int lin = p * 1024 + t * 4;
        int rn = lin >> 6, ck = lin & 63;
        bf16x4 o;
#pragma unroll
        for (int j = 0; j < 4; ++j) o[j] = (bf16)tile[ck + j][rn];
        *(bf16x4*)(Wt + (size_t)(n0 + rn) * K + k0 + ck) = o;
    }
}

// ---------------- layernorm (fp32 in, bf16 out), one row per block ----------------
__global__ __launch_bounds__(256) void ln_kernel(const float* __restrict__ in, float inScale,
                                                 const float* __restrict__ g,
                                                 const float* __restrict__ b,
                                                 bf16* __restrict__ out) {
    const int row = blockIdx.x, t = threadIdx.x;
    const float* p = in + (size_t)row * H_DIM;
    f32x4 v = *(const f32x4*)(p + t * 4);
    v *= inScale;
    float s1 = v[0] + v[1] + v[2] + v[3];
    float s2 = v[0] * v[0] + v[1] * v[1] + v[2] * v[2] + v[3] * v[3];
#pragma unroll
    for (int m = 1; m < 64; m <<= 1) {
        s1 += __shfl_xor(s1, m);
        s2 += __shfl_xor(s2, m);
    }
    __shared__ float red[8];
    const int wave = t >> 6;
    if ((t & 63) == 0) { red[wave * 2] = s1; red[wave * 2 + 1] = s2; }
    __syncthreads();
    s1 = red[0] + red[2] + red[4] + red[6];
    s2 = red[1] + red[3] + red[5] + red[7];
    float mean = s1 * (1.0f / H_DIM);
    float var  = s2 * (1.0f / H_DIM) - mean * mean;
    float inv  = rsqrtf(var + 1e-5f);
    f32x4 gg = *(const f32x4*)(g + t * 4);
    f32x4 bb = *(const f32x4*)(b + t * 4);
    bf16x4 o;
#pragma unroll
    for (int j = 0; j < 4; ++j) o[j] = (bf16)((v[j] - mean) * inv * gg[j] + bb[j]);
    *(bf16x4*)(out + (size_t)row * H_DIM + t * 4) = o;
}

// ---------------- fp32 -> bf16 with scale ----------------
__global__ __launch_bounds__(256) void cvt_scale_kernel(const float* __restrict__ in,
                                                        bf16* __restrict__ out,
                                                        float s, int n4) {
    int i = blockIdx.x * 256 + threadIdx.x;
    if (i < n4) {
        f32x4 v = *(const f32x4*)(in + (size_t)i * 4);
        bf16x4 o;
#pragma unroll
        for (int j = 0; j < 4; ++j) o[j] = (bf16)(v[j] * s);
        *(bf16x4*)(out + (size_t)i * 4) = o;
    }
}

// ---------------- GEMM: C[M,N]=A[M,K]*Bt[N,K]^T, double-buffered global_load_lds ----
// MODE 0: plain epilogue -> o1 (OUT_BF16/GELU/HAS_RES/outScale apply)
// MODE 1: QKV fused (N=3072): sec0->o1 bf16 *outScale (Q), sec1->o2 bf16 (K), sec2->o3 V-transposed
// MODE 2: KV fused  (N=2048): sec0->o1 bf16 (K), sec1->o2 V-transposed
// V-transposed layout: [b][h][d][s], s = row & (2^slog2 - 1)
template <int BM, int MODE, bool OUT_BF16, bool GELU_EPI, bool HAS_RES>
__global__ __launch_bounds__(256) void gemm_kernel(const bf16* __restrict__ A,
                                                   const bf16* __restrict__ Bt,
                                                   const float* __restrict__ bias1,
                                                   const float* __restrict__ bias2,
                                                   const float* __restrict__ bias3,
                                                   const float* __restrict__ res,
                                                   void* __restrict__ o1, void* __restrict__ o2,
                                                   void* __restrict__ o3,
                                                   int M, int N, int K,
                                                   float resScale, float outScale, int slog2) {
    constexpr int BN = 128;
    constexpr int CHUNKS = (BM + BN) / 32;       // 32-row x 64-col staging chunks
    constexpr int WRR = (BM == 128) ? 64 : 32;   // rows per wave
    constexpr int MI = WRR / 16;
    __shared__ bf16 SM[2][(BM + BN) * 64];       // linear (gload_lds dest), A then B
    const int m0 = blockIdx.y * BM, n0 = blockIdx.x * BN;
    const int tid = threadIdx.x;
    const int wave = tid >> 6, lane = tid & 63, lr = lane & 15, lhi = lane >> 4;
    const int wr = wave >> 1, wc = wave & 1;
    const int sr = lane >> 3, sc8 = (lane & 7) * 8;

    f32x4 acc[MI][4] = {};

    auto stage = [&](int buf, int k0) {
#pragma unroll
        for (int p = 0; p < CHUNKS; ++p) {
            const int rr = p * 32 + wave * 8 + sr;
            bf16* l = &SM[buf][0] + p * 2048 + wave * 512;   // wave-uniform base
            const bf16* g = (p < BM / 32)
                ? (A  + (size_t)(m0 + rr) * K + k0 + sc8)
                : (Bt + (size_t)(n0 + rr - BM) * K + k0 + sc8);
            gload_lds16(g, l);
        }
    };

    stage(0, 0);
    __syncthreads();
    int buf = 0;
    for (int k0 = 0; k0 < K; k0 += 64) {
        if (k0 + 64 < K) stage(buf ^ 1, k0 + 64);   // prefetch overlaps compute
#pragma unroll
        for (int kk = 0; kk < 2; ++kk) {
            bf16x8 af[MI], bfr[4];
#pragma unroll
            for (int i = 0; i < MI; ++i)
                af[i] = *(const bf16x8*)&SM[buf][(wr * WRR + i * 16 + lr) * 64 + kk * 32 + lhi * 8];
#pragma unroll
            for (int j = 0; j < 4; ++j)
                bfr[j] = *(const bf16x8*)&SM[buf][(BM + wc * 64 + j * 16 + lr) * 64 + kk * 32 + lhi * 8];
#pragma unroll
            for (int i = 0; i < MI; ++i)
#pragma unroll
                for (int j = 0; j < 4; ++j)
                    acc[i][j] = __builtin_amdgcn_mfma_f32_16x16x32_bf16(af[i], bfr[j], acc[i][j], 0, 0, 0);
        }
        __syncthreads();   // drains prefetch vmcnt + protects buf reuse
        buf ^= 1;
    }

#pragma unroll
    for (int i = 0; i < MI; ++i) {
#pragma unroll
        for (int j = 0; j < 4; ++j) {
            const int col = n0 + wc * 64 + j * 16 + lr;
            const int row0 = m0 + wr * WRR + i * 16 + lhi * 4;
            if (MODE == 0) {
                const float bv = bias1[col];
#pragma unroll
                for (int r = 0; r < 4; ++r) {
                    const size_t idx = (size_t)(row0 + r) * N + col;
                    float v = acc[i][j][r] + bv;
                    if (HAS_RES) v += res[idx] * resScale;
                    if (GELU_EPI) v = 0.5f * v * (1.0f + erff(v * 0.70710678118654752f));
                    v *= outScale;
                    if (OUT_BF16) ((bf16*)o1)[idx] = (bf16)v;
                    else          ((float*)o1)[idx] = v;
                }
            } else {
                const int sec = col >> 10, cl = col & 1023;
                const bool isV = (MODE == 1) ? (sec == 2) : (sec == 1);
                const float* bp = (MODE == 1) ? (sec == 0 ? bias1 : sec == 1 ? bias2 : bias3)
                                              : (sec == 0 ? bias1 : bias2);
                const float bv = bp[cl];
                if (!isV) {
                    bf16* dst = (MODE == 1) ? (sec == 0 ? (bf16*)o1 : (bf16*)o2) : (bf16*)o1;
                    const float sc = (MODE == 1 && sec == 0) ? outScale : 1.f;
#pragma unroll
                    for (int r = 0; r < 4; ++r)
                        dst[(size_t)(row0 + r) * H_DIM + cl] = (bf16)((acc[i][j][r] + bv) * sc);
                } else {
                    bf16* dst = (MODE == 1) ? (bf16*)o3 : (bf16*)o2;
                    const int S = 1 << slog2;
                    const int bI = row0 >> slog2, s0 = row0 & (S - 1);
                    const int hI = cl >> 6, dI = cl & 63;
                    bf16x4 ov;
#pragma unroll
                    for (int r = 0; r < 4; ++r) ov[r] = (bf16)(acc[i][j][r] + bv);
                    *(bf16x4*)(dst + ((size_t)((bI * NHEAD + hI) * HD + dI)) * S + s0) = ov;
                }
            }
        }
    }
}

// ---------------- flash attention v3: 128 q-rows/block, KVBLK=128, base-2 softmax ----------------
// Q pre-scaled by SCALE*log2e; Vt_g layout [b][h][d][k]; XOR-swizzled LDS.
__global__ __launch_bounds__(256) void attn_kernel(const bf16* __restrict__ Qb,
                                                   const bf16* __restrict__ Kb,
                                                   const bf16* __restrict__ Vt_g,
                                                   bf16* __restrict__ Ob,
                                                   int SQ, int SK) {
    __shared__ bf16 Kl[128 * 64];        // [key][chan], swizzled
    __shared__ bf16 Vl[64 * 128];        // [d][key], swizzled
    __shared__ bf16 Pl[4][32 * 128];     // per-wave [q][key], swizzled
    const int b = blockIdx.x >> 4, h = blockIdx.x & 15;
    const int q0 = blockIdx.y * 128;
    const int tid = threadIdx.x, wave = tid >> 6, lane = tid & 63;
    const int lr = lane & 15, lhi = lane >> 4;
    const size_t bh = (size_t)blockIdx.x;

    bf16x8 qf[2][2];
#pragma unroll
    for (int qi = 0; qi < 2; ++qi) {
        const bf16* qp = Qb + ((size_t)b * SQ + q0 + wave * 32 + qi * 16 + lr) * H_DIM + h * HD;
        qf[qi][0] = *(const bf16x8*)(qp + lhi * 8);
        qf[qi][1] = *(const bf16x8*)(qp + 32 + lhi * 8);
    }
    float mrun[2][4], lrun[2][4];
    f32x4 o[2][4] = {};
#pragma unroll
    for (int qi = 0; qi < 2; ++qi)
#pragma unroll
        for (int r = 0; r < 4; ++r) { mrun[qi][r] = -1e30f; lrun[qi][r] = 0.f; }

    for (int kb = 0; kb < SK; kb += 128) {
        __syncthreads();
#pragma unroll
        for (int p = 0; p < 4; ++p) {
            const int lin = (p * 256 + tid) * 8;
            {   // K tile: 128 keys x 64 chan
                const int r = lin >> 6, c = lin & 63;
                *(bf16x8*)&Kl[r * 64 + (c ^ ((r & 7) << 3))] =
                    *(const bf16x8*)(Kb + ((size_t)b * SK + kb + r) * H_DIM + h * HD + c);
            }
            {   // V tile: 64 d x 128 keys
                const int d = lin >> 7, ck = lin & 127;
                *(bf16x8*)&Vl[d * 128 + (ck ^ ((d & 7) << 3))] =
                    *(const bf16x8*)(Vt_g + (bh * 64 + d) * SK + kb + ck);
            }
        }
        __syncthreads();

        f32x4 s[2][8] = {};
#pragma unroll
        for (int nf = 0; nf < 8; ++nf) {
            const int kr = nf * 16 + lr;
            bf16x8 kf0 = *(const bf16x8*)&Kl[kr * 64 + ((lhi * 8) ^ ((kr & 7) << 3))];
            bf16x8 kf1 = *(const bf16x8*)&Kl[kr * 64 + ((32 + lhi * 8) ^ ((kr & 7) << 3))];
#pragma unroll
            for (int qi = 0; qi < 2; ++qi) {
                s[qi][nf] = __builtin_amdgcn_mfma_f32_16x16x32_bf16(qf[qi][0], kf0, s[qi][nf], 0, 0, 0);
                s[qi][nf] = __builtin_amdgcn_mfma_f32_16x16x32_bf16(qf[qi][1], kf1, s[qi][nf], 0, 0, 0);
            }
        }
#pragma unroll
        for (int qi = 0; qi < 2; ++qi) {
            float tm[4];
#pragma unroll
            for (int r = 0; r < 4; ++r) {
                tm[r] = s[qi][0][r];
#pragma unroll
                for (int nf = 1; nf < 8; ++nf) tm[r] = fmaxf(tm[r], s[qi][nf][r]);
            }
#pragma unroll
            for (int m = 1; m < 16; m <<= 1)
#pragma unroll
                for (int r = 0; r < 4; ++r) tm[r] = fmaxf(tm[r], __shfl_xor(tm[r], m));
            // defer-max (T13): skip rescale while tile max stays within 2^8 of running max
            bool nd = tm[0] <= mrun[qi][0] + 8.f && tm[1] <= mrun[qi][1] + 8.f &&
                      tm[2] <= mrun[qi][2] + 8.f && tm[3] <= mrun[qi][3] + 8.f;
            if (!__all(nd)) {
#pragma unroll
                for (int r = 0; r < 4; ++r) {
                    float mn = fmaxf(mrun[qi][r], tm[r]);
                    float al = exp2f(mrun[qi][r] - mn);
                    mrun[qi][r] = mn;
                    lrun[qi][r] *= al;
#pragma unroll
                    for (int df = 0; df < 4; ++df) o[qi][df][r] *= al;
                }
            }
            float rs[4] = {0.f, 0.f, 0.f, 0.f};
#pragma unroll
            for (int nf = 0; nf < 8; ++nf)
#pragma unroll
                for (int r = 0; r < 4; ++r) {
                    float pv = exp2f(s[qi][nf][r] - mrun[qi][r]);
                    rs[r] += pv;
                    const int q = qi * 16 + lhi * 4 + r, k = nf * 16 + lr;
                    Pl[wave][q * 128 + (k ^ ((q & 7) << 3))] = (bf16)pv;
                }
#pragma unroll
            for (int m = 1; m < 16; m <<= 1)
#pragma unroll
                for (int r = 0; r < 4; ++r) rs[r] += __shfl_xor(rs[r], m);
#pragma unroll
            for (int r = 0; r < 4; ++r) lrun[qi][r] += rs[r];
        }
        asm volatile("s_waitcnt lgkmcnt(0)" ::: "memory");   // Pl wave-private
#pragma unroll
        for (int kk = 0; kk < 4; ++kk) {
            bf16x8 pf[2];
#pragma unroll
            for (int qi = 0; qi < 2; ++qi) {
                const int pr = qi * 16 + lr;
                pf[qi] = *(const bf16x8*)&Pl[wave][pr * 128 + ((kk * 32 + lhi * 8) ^ ((pr & 7) << 3))];
            }
#pragma unroll
            for (int df = 0; df < 4; ++df) {
                const int vr = df * 16 + lr;
                bf16x8 vf = *(const bf16x8*)&Vl[vr * 128 + ((kk * 32 + lhi * 8) ^ ((vr & 7) << 3))];
#pragma unroll
                for (int qi = 0; qi < 2; ++qi)
                    o[qi][df] = __builtin_amdgcn_mfma_f32_16x16x32_bf16(pf[qi], vf, o[qi][df], 0, 0, 0);
            }
        }
    }
#pragma unroll
    for (int qi = 0; qi < 2; ++qi)
#pragma unroll
        for (int r = 0; r < 4; ++r) {
            const float inv = 1.0f / lrun[qi][r];
            const int qrow = q0 + wave * 32 + qi * 16 + lhi * 4 + r;
#pragma unroll
            for (int df = 0; df < 4; ++df)
                Ob[((size_t)b * SQ + qrow) * H_DIM + h * HD + df * 16 + lr] =
                    (bf16)(o[qi][df][r] * inv);
        }
}

extern "C" void kernel_launch(void* const* d_in, const int* in_sizes, int n_in,
                              void* d_out, int out_size, void* d_ws, size_t ws_size,
                              hipStream_t stream) {
    const float* x    = (const float*)d_in[0];
    const float* img  = (const float*)d_in[1];
    const float* W_sq = (const float*)d_in[2];   const float* b_sq = (const float*)d_in[3];
    const float* W_sk = (const float*)d_in[4];   const float* b_sk = (const float*)d_in[5];
    const float* W_sv = (const float*)d_in[6];   const float* b_sv = (const float*)d_in[7];
    const float* W_so = (const float*)d_in[8];   const float* b_so = (const float*)d_in[9];
    const float* W_cq = (const float*)d_in[10];  const float* b_cq = (const float*)d_in[11];
    const float* W_ck = (const float*)d_in[12];  const float* b_ck = (const float*)d_in[13];
    const float* W_cv = (const float*)d_in[14];  const float* b_cv = (const float*)d_in[15];
    const float* W_co = (const float*)d_in[16];  const float* b_co = (const float*)d_in[17];
    const float* W_f1 = (const float*)d_in[18];  const float* b_f1 = (const float*)d_in[19];
    const float* W_f2 = (const float*)d_in[20];  const float* b_f2 = (const float*)d_in[21];
    const float* g1 = (const float*)d_in[22];    const float* bb1 = (const float*)d_in[23];
    const float* g2 = (const float*)d_in[24];    const float* bb2 = (const float*)d_in[25];
    const float* g3 = (const float*)d_in[26];    const float* bb3 = (const float*)d_in[27];

    char* ws = (char*)d_ws;
    const size_t MB = 1ull << 20;
    bf16* WT   = (bf16*)ws;
    bf16* w_sq = WT + 0 * (1u << 20);   // sq,sk,sv contiguous -> fused QKV weight [3072][1024]
    bf16* w_sk = WT + 1 * (1u << 20);
    bf16* w_sv = WT + 2 * (1u << 20);
    bf16* w_so = WT + 3 * (1u << 20);
    bf16* w_cq = WT + 4 * (1u << 20);
    bf16* w_ck = WT + 5 * (1u << 20);   // ck,cv contiguous -> fused KV weight [2048][1024]
    bf16* w_cv = WT + 6 * (1u << 20);
    bf16* w_co = WT + 7 * (1u << 20);
    bf16* w_f1 = WT + 8 * (1u << 20);   // [4096][1024]
    bf16* w_f2 = WT + 12 * (1u << 20);  // [1024][4096]
    float* XR  = (float*)(ws + 32 * MB);
    bf16* NX   = (bf16*)(ws + 48 * MB);
    bf16* Qb   = (bf16*)(ws + 56 * MB);
    bf16* Kb   = (bf16*)(ws + 64 * MB);
    bf16* Vt   = (bf16*)(ws + 72 * MB);  // [b][h][d][s]
    bf16* FF   = (bf16*)(ws + 56 * MB);  // reused after attention
    bf16* IMGB = (bf16*)(ws + 88 * MB);

    const dim3 blk(256);

    wconv_kernel<<<dim3(16, 16), blk, 0, stream>>>(W_sq, w_sq, 1024, 1024);
    wconv_kernel<<<dim3(16, 16), blk, 0, stream>>>(W_sk, w_sk, 1024, 1024);
    wconv_kernel<<<dim3(16, 16), blk, 0, stream>>>(W_sv, w_sv, 1024, 1024);
    wconv_kernel<<<dim3(16, 16), blk, 0, stream>>>(W_so, w_so, 1024, 1024);
    wconv_kernel<<<dim3(16, 16), blk, 0, stream>>>(W_cq, w_cq, 1024, 1024);
    wconv_kernel<<<dim3(16, 16), blk, 0, stream>>>(W_ck, w_ck, 1024, 1024);
    wconv_kernel<<<dim3(16, 16), blk, 0, stream>>>(W_cv, w_cv, 1024, 1024);
    wconv_kernel<<<dim3(16, 16), blk, 0, stream>>>(W_co, w_co, 1024, 1024);
    wconv_kernel<<<dim3(64, 16), blk, 0, stream>>>(W_f1, w_f1, 1024, 4096);
    wconv_kernel<<<dim3(16, 64), blk, 0, stream>>>(W_f2, w_f2, 4096, 1024);

    // ---- self attention ----
    ln_kernel<<<4096, blk, 0, stream>>>(x, 0.1f, g1, bb1, NX);
    gemm_kernel<128, 1, true, false, false><<<dim3(24, 32), blk, 0, stream>>>(
        NX, w_sq, b_sq, b_sk, b_sv, nullptr, Qb, Kb, Vt, 4096, 3072, 1024, 0.f, QSCL, 11);
    attn_kernel<<<dim3(32, 16), blk, 0, stream>>>(Qb, Kb, Vt, NX, 2048, 2048);
    gemm_kernel<64, 0, false, false, true><<<dim3(8, 64), blk, 0, stream>>>(
        NX, w_so, b_so, nullptr, nullptr, x, XR, nullptr, nullptr, 4096, 1024, 1024, 0.1f, 1.f, 0);

    // ---- cross attention ----
    ln_kernel<<<4096, blk, 0, stream>>>(XR, 1.f, g2, bb2, NX);
    gemm_kernel<64, 0, true, false, false><<<dim3(8, 64), blk, 0, stream>>>(
        NX, w_cq, b_cq, nullptr, nullptr, nullptr, Qb, nullptr, nullptr, 4096, 1024, 1024, 0.f, QSCL, 0);
    cvt_scale_kernel<<<dim3(512), blk, 0, stream>>>(img, IMGB, 0.1f, 131072);
    gemm_kernel<64, 2, true, false, false><<<dim3(16, 8), blk, 0, stream>>>(
        IMGB, w_ck, b_ck, b_cv, nullptr, nullptr, Kb, Vt, nullptr, 512, 2048, 1024, 0.f, 1.f, 8);
    attn_kernel<<<dim3(32, 16), blk, 0, stream>>>(Qb, Kb, Vt, NX, 2048, 256);
    gemm_kernel<64, 0, false, false, true><<<dim3(8, 64), blk, 0, stream>>>(
        NX, w_co, b_co, nullptr, nullptr, XR, XR, nullptr, nullptr, 4096, 1024, 1024, 1.f, 1.f, 0);

    // ---- feed forward ----
    ln_kernel<<<4096, blk, 0, stream>>>(XR, 1.f, g3, bb3, NX);
    gemm_kernel<128, 0, true, true, false><<<dim3(32, 32), blk, 0, stream>>>(
        NX, w_f1, b_f1, nullptr, nullptr, nullptr, FF, nullptr, nullptr, 4096, 4096, 1024, 0.f, 1.f, 0);
    gemm_kernel<64, 0, false, false, true><<<dim3(8, 64), blk, 0, stream>>>(
        FF, w_f2, b_f2, nullptr, nullptr, XR, d_out, nullptr, nullptr, 4096, 1024, 4096, 1.f, 10.f, 0);
}

// Round 5
// 424.658 us; speedup vs baseline: 1.3204x; 1.0361x over previous
//
#include <hip/hip_runtime.h>
#include <hip/hip_bf16.h>

typedef __bf16 bf16;
typedef __bf16 bf16x4 __attribute__((ext_vector_type(4)));
typedef __bf16 bf16x8 __attribute__((ext_vector_type(8)));
typedef float  f32x4  __attribute__((ext_vector_type(4)));

#define H_DIM 1024
#define NHEAD 16
#define HD    64
// SCALE * log2(e), folded into Q-projection epilogue; attn softmax runs in base-2
#define QSCL 0.18033688011112042f

__device__ __forceinline__ void gload_lds16(const bf16* g, bf16* l) {
    __builtin_amdgcn_global_load_lds((const __attribute__((address_space(1))) void*)g,
                                     (__attribute__((address_space(3))) void*)l, 16, 0, 0);
}

// DPP row_ror:N rotate within each 16-lane row (VALU-rate cross-lane, no LDS pipe)
template <int N>
__device__ __forceinline__ float dpp_ror(float x) {
    int r = __builtin_amdgcn_update_dpp(0, __builtin_bit_cast(int, x),
                                        0x120 | N, 0xF, 0xF, true);
    return __builtin_bit_cast(float, r);
}
__device__ __forceinline__ float row_max16(float x) {
    x = fmaxf(x, dpp_ror<1>(x));
    x = fmaxf(x, dpp_ror<2>(x));
    x = fmaxf(x, dpp_ror<4>(x));
    x = fmaxf(x, dpp_ror<8>(x));
    return x;   // all 16 lanes of the row hold the max
}
__device__ __forceinline__ float row_sum16(float x) {
    x += dpp_ror<1>(x);
    x += dpp_ror<2>(x);
    x += dpp_ror<4>(x);
    x += dpp_ror<8>(x);
    return x;
}

// ---------------- weight fp32 [K][N] -> bf16 [N][K] (transpose+convert) ----------------
__global__ __launch_bounds__(256) void wconv_kernel(const float* __restrict__ W,
                                                    bf16* __restrict__ Wt,
                                                    int K, int N) {
    __shared__ float tile[64][65];
    const int n0 = blockIdx.x * 64, k0 = blockIdx.y * 64;
    const int t = threadIdx.x;
#pragma unroll
    for (int p = 0; p < 4; ++p) {
        int lin = p * 1024 + t * 4;
        int r = lin >> 6, c = lin & 63;
        f32x4 v = *(const f32x4*)(W + (size_t)(k0 + r) * N + n0 + c);
        tile[r][c]     = v[0];
        tile[r][c + 1] = v[1];
        tile[r][c + 2] = v[2];
        tile[r][c + 3] = v[3];
    }
    __syncthreads();
#pragma unroll
    for (int p = 0; p < 4; ++p) {
        int lin = p * 1024 + t * 4;
        int rn = lin >> 6, ck = lin & 63;
        bf16x4 o;
#pragma unroll
        for (int j = 0; j < 4; ++j) o[j] = (bf16)tile[ck + j][rn];
        *(bf16x4*)(Wt + (size_t)(n0 + rn) * K + k0 + ck) = o;
    }
}

// ---------------- layernorm (fp32 in, bf16 out), one row per block ----------------
__global__ __launch_bounds__(256) void ln_kernel(const float* __restrict__ in, float inScale,
                                                 const float* __restrict__ g,
                                                 const float* __restrict__ b,
                                                 bf16* __restrict__ out) {
    const int row = blockIdx.x, t = threadIdx.x;
    const float* p = in + (size_t)row * H_DIM;
    f32x4 v = *(const f32x4*)(p + t * 4);
    v *= inScale;
    float s1 = v[0] + v[1] + v[2] + v[3];
    float s2 = v[0] * v[0] + v[1] * v[1] + v[2] * v[2] + v[3] * v[3];
#pragma unroll
    for (int m = 1; m < 64; m <<= 1) {
        s1 += __shfl_xor(s1, m);
        s2 += __shfl_xor(s2, m);
    }
    __shared__ float red[8];
    const int wave = t >> 6;
    if ((t & 63) == 0) { red[wave * 2] = s1; red[wave * 2 + 1] = s2; }
    __syncthreads();
    s1 = red[0] + red[2] + red[4] + red[6];
    s2 = red[1] + red[3] + red[5] + red[7];
    float mean = s1 * (1.0f / H_DIM);
    float var  = s2 * (1.0f / H_DIM) - mean * mean;
    float inv  = rsqrtf(var + 1e-5f);
    f32x4 gg = *(const f32x4*)(g + t * 4);
    f32x4 bb = *(const f32x4*)(b + t * 4);
    bf16x4 o;
#pragma unroll
    for (int j = 0; j < 4; ++j) o[j] = (bf16)((v[j] - mean) * inv * gg[j] + bb[j]);
    *(bf16x4*)(out + (size_t)row * H_DIM + t * 4) = o;
}

// ---------------- fp32 -> bf16 with scale ----------------
__global__ __launch_bounds__(256) void cvt_scale_kernel(const float* __restrict__ in,
                                                        bf16* __restrict__ out,
                                                        float s, int n4) {
    int i = blockIdx.x * 256 + threadIdx.x;
    if (i < n4) {
        f32x4 v = *(const f32x4*)(in + (size_t)i * 4);
        bf16x4 o;
#pragma unroll
        for (int j = 0; j < 4; ++j) o[j] = (bf16)(v[j] * s);
        *(bf16x4*)(out + (size_t)i * 4) = o;
    }
}

// ---------------- GEMM: C[M,N]=A[M,K]*Bt[N,K]^T, double-buffered global_load_lds ----
// MODE 0: plain epilogue -> o1 (OUT_BF16/GELU/HAS_RES/outScale apply)
// MODE 1: QKV fused (N=3072): sec0->o1 bf16 *outScale (Q), sec1->o2 bf16 (K), sec2->o3 V-transposed
// MODE 2: KV fused  (N=2048): sec0->o1 bf16 (K), sec1->o2 V-transposed
// V-transposed layout: [b][h][d][s], s = row & (2^slog2 - 1)
template <int BM, int MODE, bool OUT_BF16, bool GELU_EPI, bool HAS_RES>
__global__ __launch_bounds__(256) void gemm_kernel(const bf16* __restrict__ A,
                                                   const bf16* __restrict__ Bt,
                                                   const float* __restrict__ bias1,
                                                   const float* __restrict__ bias2,
                                                   const float* __restrict__ bias3,
                                                   const float* __restrict__ res,
                                                   void* __restrict__ o1, void* __restrict__ o2,
                                                   void* __restrict__ o3,
                                                   int M, int N, int K,
                                                   float resScale, float outScale, int slog2) {
    constexpr int BN = 128;
    constexpr int CHUNKS = (BM + BN) / 32;       // 32-row x 64-col staging chunks
    constexpr int WRR = (BM == 128) ? 64 : 32;   // rows per wave
    constexpr int MI = WRR / 16;
    __shared__ bf16 SM[2][(BM + BN) * 64];       // linear (gload_lds dest), A then B
    const int m0 = blockIdx.y * BM, n0 = blockIdx.x * BN;
    const int tid = threadIdx.x;
    const int wave = tid >> 6, lane = tid & 63, lr = lane & 15, lhi = lane >> 4;
    const int wr = wave >> 1, wc = wave & 1;
    const int sr = lane >> 3, sc8 = (lane & 7) * 8;

    f32x4 acc[MI][4] = {};

    auto stage = [&](int buf, int k0) {
#pragma unroll
        for (int p = 0; p < CHUNKS; ++p) {
            const int rr = p * 32 + wave * 8 + sr;
            bf16* l = &SM[buf][0] + p * 2048 + wave * 512;   // wave-uniform base
            const bf16* g = (p < BM / 32)
                ? (A  + (size_t)(m0 + rr) * K + k0 + sc8)
                : (Bt + (size_t)(n0 + rr - BM) * K + k0 + sc8);
            gload_lds16(g, l);
        }
    };

    stage(0, 0);
    __syncthreads();
    int buf = 0;
    for (int k0 = 0; k0 < K; k0 += 64) {
        if (k0 + 64 < K) stage(buf ^ 1, k0 + 64);   // prefetch overlaps compute
#pragma unroll
        for (int kk = 0; kk < 2; ++kk) {
            bf16x8 af[MI], bfr[4];
#pragma unroll
            for (int i = 0; i < MI; ++i)
                af[i] = *(const bf16x8*)&SM[buf][(wr * WRR + i * 16 + lr) * 64 + kk * 32 + lhi * 8];
#pragma unroll
            for (int j = 0; j < 4; ++j)
                bfr[j] = *(const bf16x8*)&SM[buf][(BM + wc * 64 + j * 16 + lr) * 64 + kk * 32 + lhi * 8];
#pragma unroll
            for (int i = 0; i < MI; ++i)
#pragma unroll
                for (int j = 0; j < 4; ++j)
                    acc[i][j] = __builtin_amdgcn_mfma_f32_16x16x32_bf16(af[i], bfr[j], acc[i][j], 0, 0, 0);
        }
        __syncthreads();   // drains prefetch vmcnt + protects buf reuse
        buf ^= 1;
    }

#pragma unroll
    for (int i = 0; i < MI; ++i) {
#pragma unroll
        for (int j = 0; j < 4; ++j) {
            const int col = n0 + wc * 64 + j * 16 + lr;
            const int row0 = m0 + wr * WRR + i * 16 + lhi * 4;
            if (MODE == 0) {
                const float bv = bias1[col];
#pragma unroll
                for (int r = 0; r < 4; ++r) {
                    const size_t idx = (size_t)(row0 + r) * N + col;
                    float v = acc[i][j][r] + bv;
                    if (HAS_RES) v += res[idx] * resScale;
                    if (GELU_EPI) v = 0.5f * v * (1.0f + erff(v * 0.70710678118654752f));
                    v *= outScale;
                    if (OUT_BF16) ((bf16*)o1)[idx] = (bf16)v;
                    else          ((float*)o1)[idx] = v;
                }
            } else {
                const int sec = col >> 10, cl = col & 1023;
                const bool isV = (MODE == 1) ? (sec == 2) : (sec == 1);
                const float* bp = (MODE == 1) ? (sec == 0 ? bias1 : sec == 1 ? bias2 : bias3)
                                              : (sec == 0 ? bias1 : bias2);
                const float bv = bp[cl];
                if (!isV) {
                    bf16* dst = (MODE == 1) ? (sec == 0 ? (bf16*)o1 : (bf16*)o2) : (bf16*)o1;
                    const float sc = (MODE == 1 && sec == 0) ? outScale : 1.f;
#pragma unroll
                    for (int r = 0; r < 4; ++r)
                        dst[(size_t)(row0 + r) * H_DIM + cl] = (bf16)((acc[i][j][r] + bv) * sc);
                } else {
                    bf16* dst = (MODE == 1) ? (bf16*)o3 : (bf16*)o2;
                    const int S = 1 << slog2;
                    const int bI = row0 >> slog2, s0 = row0 & (S - 1);
                    const int hI = cl >> 6, dI = cl & 63;
                    bf16x4 ov;
#pragma unroll
                    for (int r = 0; r < 4; ++r) ov[r] = (bf16)(acc[i][j][r] + bv);
                    *(bf16x4*)(dst + ((size_t)((bI * NHEAD + hI) * HD + dI)) * S + s0) = ov;
                }
            }
        }
    }
}

// ---------------- flash attention v4: DPP softmax reductions (VALU-rate cross-lane) ----------------
// Q pre-scaled by SCALE*log2e; Vt_g layout [b][h][d][k]; XOR-swizzled LDS.
__global__ __launch_bounds__(256) void attn_kernel(const bf16* __restrict__ Qb,
                                                   const bf16* __restrict__ Kb,
                                                   const bf16* __restrict__ Vt_g,
                                                   bf16* __restrict__ Ob,
                                                   int SQ, int SK) {
    __shared__ bf16 Kl[128 * 64];        // [key][chan], swizzled
    __shared__ bf16 Vl[64 * 128];        // [d][key], swizzled
    __shared__ bf16 Pl[4][32 * 128];     // per-wave [q][key], swizzled
    const int b = blockIdx.x >> 4, h = blockIdx.x & 15;
    const int q0 = blockIdx.y * 128;
    const int tid = threadIdx.x, wave = tid >> 6, lane = tid & 63;
    const int lr = lane & 15, lhi = lane >> 4;
    const size_t bh = (size_t)blockIdx.x;

    bf16x8 qf[2][2];
#pragma unroll
    for (int qi = 0; qi < 2; ++qi) {
        const bf16* qp = Qb + ((size_t)b * SQ + q0 + wave * 32 + qi * 16 + lr) * H_DIM + h * HD;
        qf[qi][0] = *(const bf16x8*)(qp + lhi * 8);
        qf[qi][1] = *(const bf16x8*)(qp + 32 + lhi * 8);
    }
    float mrun[2][4], lrun[2][4];
    f32x4 o[2][4] = {};
#pragma unroll
    for (int qi = 0; qi < 2; ++qi)
#pragma unroll
        for (int r = 0; r < 4; ++r) { mrun[qi][r] = -1e30f; lrun[qi][r] = 0.f; }

    for (int kb = 0; kb < SK; kb += 128) {
        __syncthreads();
#pragma unroll
        for (int p = 0; p < 4; ++p) {
            const int lin = (p * 256 + tid) * 8;
            {   // K tile: 128 keys x 64 chan
                const int r = lin >> 6, c = lin & 63;
                *(bf16x8*)&Kl[r * 64 + (c ^ ((r & 7) << 3))] =
                    *(const bf16x8*)(Kb + ((size_t)b * SK + kb + r) * H_DIM + h * HD + c);
            }
            {   // V tile: 64 d x 128 keys
                const int d = lin >> 7, ck = lin & 127;
                *(bf16x8*)&Vl[d * 128 + (ck ^ ((d & 7) << 3))] =
                    *(const bf16x8*)(Vt_g + (bh * 64 + d) * SK + kb + ck);
            }
        }
        __syncthreads();

        f32x4 s[2][8] = {};
#pragma unroll
        for (int nf = 0; nf < 8; ++nf) {
            const int kr = nf * 16 + lr;
            bf16x8 kf0 = *(const bf16x8*)&Kl[kr * 64 + ((lhi * 8) ^ ((kr & 7) << 3))];
            bf16x8 kf1 = *(const bf16x8*)&Kl[kr * 64 + ((32 + lhi * 8) ^ ((kr & 7) << 3))];
#pragma unroll
            for (int qi = 0; qi < 2; ++qi) {
                s[qi][nf] = __builtin_amdgcn_mfma_f32_16x16x32_bf16(qf[qi][0], kf0, s[qi][nf], 0, 0, 0);
                s[qi][nf] = __builtin_amdgcn_mfma_f32_16x16x32_bf16(qf[qi][1], kf1, s[qi][nf], 0, 0, 0);
            }
        }
#pragma unroll
        for (int qi = 0; qi < 2; ++qi) {
            float tm[4];
#pragma unroll
            for (int r = 0; r < 4; ++r) {
                // tree max over 8 frags, then DPP rotate-reduce over the 16-lane row
                float a0 = fmaxf(s[qi][0][r], s[qi][1][r]);
                float a1 = fmaxf(s[qi][2][r], s[qi][3][r]);
                float a2 = fmaxf(s[qi][4][r], s[qi][5][r]);
                float a3 = fmaxf(s[qi][6][r], s[qi][7][r]);
                tm[r] = row_max16(fmaxf(fmaxf(a0, a1), fmaxf(a2, a3)));
            }
            // defer-max (T13): skip rescale while tile max stays within 2^8 of running max
            bool nd = tm[0] <= mrun[qi][0] + 8.f && tm[1] <= mrun[qi][1] + 8.f &&
                      tm[2] <= mrun[qi][2] + 8.f && tm[3] <= mrun[qi][3] + 8.f;
            if (!__all(nd)) {
#pragma unroll
                for (int r = 0; r < 4; ++r) {
                    float mn = fmaxf(mrun[qi][r], tm[r]);
                    float al = exp2f(mrun[qi][r] - mn);
                    mrun[qi][r] = mn;
                    lrun[qi][r] *= al;
#pragma unroll
                    for (int df = 0; df < 4; ++df) o[qi][df][r] *= al;
                }
            }
            float rs[4] = {0.f, 0.f, 0.f, 0.f};
#pragma unroll
            for (int nf = 0; nf < 8; ++nf)
#pragma unroll
                for (int r = 0; r < 4; ++r) {
                    float pv = exp2f(s[qi][nf][r] - mrun[qi][r]);
                    rs[r] += pv;
                    const int q = qi * 16 + lhi * 4 + r, k = nf * 16 + lr;
                    Pl[wave][q * 128 + (k ^ ((q & 7) << 3))] = (bf16)pv;
                }
#pragma unroll
            for (int r = 0; r < 4; ++r) lrun[qi][r] += row_sum16(rs[r]);
        }
        asm volatile("s_waitcnt lgkmcnt(0)" ::: "memory");   // Pl wave-private
#pragma unroll
        for (int kk = 0; kk < 4; ++kk) {
            bf16x8 pf[2];
#pragma unroll
            for (int qi = 0; qi < 2; ++qi) {
                const int pr = qi * 16 + lr;
                pf[qi] = *(const bf16x8*)&Pl[wave][pr * 128 + ((kk * 32 + lhi * 8) ^ ((pr & 7) << 3))];
            }
#pragma unroll
            for (int df = 0; df < 4; ++df) {
                const int vr = df * 16 + lr;
                bf16x8 vf = *(const bf16x8*)&Vl[vr * 128 + ((kk * 32 + lhi * 8) ^ ((vr & 7) << 3))];
#pragma unroll
                for (int qi = 0; qi < 2; ++qi)
                    o[qi][df] = __builtin_amdgcn_mfma_f32_16x16x32_bf16(pf[qi], vf, o[qi][df], 0, 0, 0);
            }
        }
    }
#pragma unroll
    for (int qi = 0; qi < 2; ++qi)
#pragma unroll
        for (int r = 0; r < 4; ++r) {
            const float inv = 1.0f / lrun[qi][r];
            const int qrow = q0 + wave * 32 + qi * 16 + lhi * 4 + r;
#pragma unroll
            for (int df = 0; df < 4; ++df)
                Ob[((size_t)b * SQ + qrow) * H_DIM + h * HD + df * 16 + lr] =
                    (bf16)(o[qi][df][r] * inv);
        }
}

extern "C" void kernel_launch(void* const* d_in, const int* in_sizes, int n_in,
                              void* d_out, int out_size, void* d_ws, size_t ws_size,
                              hipStream_t stream) {
    const float* x    = (const float*)d_in[0];
    const float* img  = (const float*)d_in[1];
    const float* W_sq = (const float*)d_in[2];   const float* b_sq = (const float*)d_in[3];
    const float* W_sk = (const float*)d_in[4];   const float* b_sk = (const float*)d_in[5];
    const float* W_sv = (const float*)d_in[6];   const float* b_sv = (const float*)d_in[7];
    const float* W_so = (const float*)d_in[8];   const float* b_so = (const float*)d_in[9];
    const float* W_cq = (const float*)d_in[10];  const float* b_cq = (const float*)d_in[11];
    const float* W_ck = (const float*)d_in[12];  const float* b_ck = (const float*)d_in[13];
    const float* W_cv = (const float*)d_in[14];  const float* b_cv = (const float*)d_in[15];
    const float* W_co = (const float*)d_in[16];  const float* b_co = (const float*)d_in[17];
    const float* W_f1 = (const float*)d_in[18];  const float* b_f1 = (const float*)d_in[19];
    const float* W_f2 = (const float*)d_in[20];  const float* b_f2 = (const float*)d_in[21];
    const float* g1 = (const float*)d_in[22];    const float* bb1 = (const float*)d_in[23];
    const float* g2 = (const float*)d_in[24];    const float* bb2 = (const float*)d_in[25];
    const float* g3 = (const float*)d_in[26];    const float* bb3 = (const float*)d_in[27];

    char* ws = (char*)d_ws;
    const size_t MB = 1ull << 20;
    bf16* WT   = (bf16*)ws;
    bf16* w_sq = WT + 0 * (1u << 20);   // sq,sk,sv contiguous -> fused QKV weight [3072][1024]
    bf16* w_sk = WT + 1 * (1u << 20);
    bf16* w_sv = WT + 2 * (1u << 20);
    bf16* w_so = WT + 3 * (1u << 20);
    bf16* w_cq = WT + 4 * (1u << 20);
    bf16* w_ck = WT + 5 * (1u << 20);   // ck,cv contiguous -> fused KV weight [2048][1024]
    bf16* w_cv = WT + 6 * (1u << 20);
    bf16* w_co = WT + 7 * (1u << 20);
    bf16* w_f1 = WT + 8 * (1u << 20);   // [4096][1024]
    bf16* w_f2 = WT + 12 * (1u << 20);  // [1024][4096]
    float* XR  = (float*)(ws + 32 * MB);
    bf16* NX   = (bf16*)(ws + 48 * MB);
    bf16* Qb   = (bf16*)(ws + 56 * MB);
    bf16* Kb   = (bf16*)(ws + 64 * MB);
    bf16* Vt   = (bf16*)(ws + 72 * MB);  // [b][h][d][s]
    bf16* FF   = (bf16*)(ws + 56 * MB);  // reused after attention
    bf16* IMGB = (bf16*)(ws + 88 * MB);

    const dim3 blk(256);

    wconv_kernel<<<dim3(16, 16), blk, 0, stream>>>(W_sq, w_sq, 1024, 1024);
    wconv_kernel<<<dim3(16, 16), blk, 0, stream>>>(W_sk, w_sk, 1024, 1024);
    wconv_kernel<<<dim3(16, 16), blk, 0, stream>>>(W_sv, w_sv, 1024, 1024);
    wconv_kernel<<<dim3(16, 16), blk, 0, stream>>>(W_so, w_so, 1024, 1024);
    wconv_kernel<<<dim3(16, 16), blk, 0, stream>>>(W_cq, w_cq, 1024, 1024);
    wconv_kernel<<<dim3(16, 16), blk, 0, stream>>>(W_ck, w_ck, 1024, 1024);
    wconv_kernel<<<dim3(16, 16), blk, 0, stream>>>(W_cv, w_cv, 1024, 1024);
    wconv_kernel<<<dim3(16, 16), blk, 0, stream>>>(W_co, w_co, 1024, 1024);
    wconv_kernel<<<dim3(64, 16), blk, 0, stream>>>(W_f1, w_f1, 1024, 4096);
    wconv_kernel<<<dim3(16, 64), blk, 0, stream>>>(W_f2, w_f2, 4096, 1024);

    // ---- self attention ----
    ln_kernel<<<4096, blk, 0, stream>>>(x, 0.1f, g1, bb1, NX);
    gemm_kernel<128, 1, true, false, false><<<dim3(24, 32), blk, 0, stream>>>(
        NX, w_sq, b_sq, b_sk, b_sv, nullptr, Qb, Kb, Vt, 4096, 3072, 1024, 0.f, QSCL, 11);
    attn_kernel<<<dim3(32, 16), blk, 0, stream>>>(Qb, Kb, Vt, NX, 2048, 2048);
    gemm_kernel<64, 0, false, false, true><<<dim3(8, 64), blk, 0, stream>>>(
        NX, w_so, b_so, nullptr, nullptr, x, XR, nullptr, nullptr, 4096, 1024, 1024, 0.1f, 1.f, 0);

    // ---- cross attention ----
    ln_kernel<<<4096, blk, 0, stream>>>(XR, 1.f, g2, bb2, NX);
    gemm_kernel<64, 0, true, false, false><<<dim3(8, 64), blk, 0, stream>>>(
        NX, w_cq, b_cq, nullptr, nullptr, nullptr, Qb, nullptr, nullptr, 4096, 1024, 1024, 0.f, QSCL, 0);
    cvt_scale_kernel<<<dim3(512), blk, 0, stream>>>(img, IMGB, 0.1f, 131072);
    gemm_kernel<64, 2, true, false, false><<<dim3(16, 8), blk, 0, stream>>>(
        IMGB, w_ck, b_ck, b_cv, nullptr, nullptr, Kb, Vt, nullptr, 512, 2048, 1024, 0.f, 1.f, 8);
    attn_kernel<<<dim3(32, 16), blk, 0, stream>>>(Qb, Kb, Vt, NX, 2048, 256);
    gemm_kernel<64, 0, false, false, true><<<dim3(8, 64), blk, 0, stream>>>(
        NX, w_co, b_co, nullptr, nullptr, XR, XR, nullptr, nullptr, 4096, 1024, 1024, 1.f, 1.f, 0);

    // ---- feed forward ----
    ln_kernel<<<4096, blk, 0, stream>>>(XR, 1.f, g3, bb3, NX);
    gemm_kernel<128, 0, true, true, false><<<dim3(32, 32), blk, 0, stream>>>(
        NX, w_f1, b_f1, nullptr, nullptr, nullptr, FF, nullptr, nullptr, 4096, 4096, 1024, 0.f, 1.f, 0);
    gemm_kernel<64, 0, false, false, true><<<dim3(8, 64), blk, 0, stream>>>(
        FF, w_f2, b_f2, nullptr, nullptr, XR, d_out, nullptr, nullptr, 4096, 1024, 4096, 1.f, 10.f, 0);
}

// Round 6
// 389.317 us; speedup vs baseline: 1.4403x; 1.0908x over previous
//
#include <hip/hip_runtime.h>
#include <hip/hip_bf16.h>

typedef __bf16 bf16;
typedef __bf16 bf16x4 __attribute__((ext_vector_type(4)));
typedef __bf16 bf16x8 __attribute__((ext_vector_type(8)));
typedef float  f32x4  __attribute__((ext_vector_type(4)));
typedef int    int4v  __attribute__((ext_vector_type(4)));

#define H_DIM 1024
#define NHEAD 16
#define HD    64
// SCALE * log2(e), folded into Q-projection epilogue; attn softmax runs in base-2
#define QSCL 0.18033688011112042f

__device__ __forceinline__ void gload_lds16(const bf16* g, bf16* l) {
    __builtin_amdgcn_global_load_lds((const __attribute__((address_space(1))) void*)g,
                                     (__attribute__((address_space(3))) void*)l, 16, 0, 0);
}

__device__ __forceinline__ unsigned cvtpk_bf16(float lo, float hi) {
    unsigned r;
    asm volatile("v_cvt_pk_bf16_f32 %0, %1, %2" : "=v"(r) : "v"(lo), "v"(hi));
    return r;
}

// ---------------- weight fp32 [K][N] -> bf16 [N][K] (transpose+convert) ----------------
__global__ __launch_bounds__(256) void wconv_kernel(const float* __restrict__ W,
                                                    bf16* __restrict__ Wt,
                                                    int K, int N) {
    __shared__ float tile[64][65];
    const int n0 = blockIdx.x * 64, k0 = blockIdx.y * 64;
    const int t = threadIdx.x;
#pragma unroll
    for (int p = 0; p < 4; ++p) {
        int lin = p * 1024 + t * 4;
        int r = lin >> 6, c = lin & 63;
        f32x4 v = *(const f32x4*)(W + (size_t)(k0 + r) * N + n0 + c);
        tile[r][c]     = v[0];
        tile[r][c + 1] = v[1];
        tile[r][c + 2] = v[2];
        tile[r][c + 3] = v[3];
    }
    __syncthreads();
#pragma unroll
    for (int p = 0; p < 4; ++p) {
        int lin = p * 1024 + t * 4;
        int rn = lin >> 6, ck = lin & 63;
        bf16x4 o;
#pragma unroll
        for (int j = 0; j < 4; ++j) o[j] = (bf16)tile[ck + j][rn];
        *(bf16x4*)(Wt + (size_t)(n0 + rn) * K + k0 + ck) = o;
    }
}

// ---------------- layernorm (fp32 in, bf16 out), one row per block ----------------
__global__ __launch_bounds__(256) void ln_kernel(const float* __restrict__ in, float inScale,
                                                 const float* __restrict__ g,
                                                 const float* __restrict__ b,
                                                 bf16* __restrict__ out) {
    const int row = blockIdx.x, t = threadIdx.x;
    const float* p = in + (size_t)row * H_DIM;
    f32x4 v = *(const f32x4*)(p + t * 4);
    v *= inScale;
    float s1 = v[0] + v[1] + v[2] + v[3];
    float s2 = v[0] * v[0] + v[1] * v[1] + v[2] * v[2] + v[3] * v[3];
#pragma unroll
    for (int m = 1; m < 64; m <<= 1) {
        s1 += __shfl_xor(s1, m);
        s2 += __shfl_xor(s2, m);
    }
    __shared__ float red[8];
    const int wave = t >> 6;
    if ((t & 63) == 0) { red[wave * 2] = s1; red[wave * 2 + 1] = s2; }
    __syncthreads();
    s1 = red[0] + red[2] + red[4] + red[6];
    s2 = red[1] + red[3] + red[5] + red[7];
    float mean = s1 * (1.0f / H_DIM);
    float var  = s2 * (1.0f / H_DIM) - mean * mean;
    float inv  = rsqrtf(var + 1e-5f);
    f32x4 gg = *(const f32x4*)(g + t * 4);
    f32x4 bb = *(const f32x4*)(b + t * 4);
    bf16x4 o;
#pragma unroll
    for (int j = 0; j < 4; ++j) o[j] = (bf16)((v[j] - mean) * inv * gg[j] + bb[j]);
    *(bf16x4*)(out + (size_t)row * H_DIM + t * 4) = o;
}

// ---------------- fp32 -> bf16 with scale ----------------
__global__ __launch_bounds__(256) void cvt_scale_kernel(const float* __restrict__ in,
                                                        bf16* __restrict__ out,
                                                        float s, int n4) {
    int i = blockIdx.x * 256 + threadIdx.x;
    if (i < n4) {
        f32x4 v = *(const f32x4*)(in + (size_t)i * 4);
        bf16x4 o;
#pragma unroll
        for (int j = 0; j < 4; ++j) o[j] = (bf16)(v[j] * s);
        *(bf16x4*)(out + (size_t)i * 4) = o;
    }
}

// ---------------- GEMM: C[M,N]=A[M,K]*Bt[N,K]^T, double-buffered global_load_lds ----
// MODE 0: plain epilogue -> o1 (OUT_BF16/GELU/HAS_RES/outScale apply)
// MODE 1: QKV fused (N=3072): sec0->o1 bf16 *outScale (Q), sec1->o2 bf16 (K), sec2->o3 V-transposed
// MODE 2: KV fused  (N=2048): sec0->o1 bf16 (K), sec1->o2 V-transposed
// V-transposed layout: [b][h][d][s], s = row & (2^slog2 - 1)
template <int BM, int MODE, bool OUT_BF16, bool GELU_EPI, bool HAS_RES>
__global__ __launch_bounds__(256) void gemm_kernel(const bf16* __restrict__ A,
                                                   const bf16* __restrict__ Bt,
                                                   const float* __restrict__ bias1,
                                                   const float* __restrict__ bias2,
                                                   const float* __restrict__ bias3,
                                                   const float* __restrict__ res,
                                                   void* __restrict__ o1, void* __restrict__ o2,
                                                   void* __restrict__ o3,
                                                   int M, int N, int K,
                                                   float resScale, float outScale, int slog2) {
    constexpr int BN = 128;
    constexpr int CHUNKS = (BM + BN) / 32;       // 32-row x 64-col staging chunks
    constexpr int WRR = (BM == 128) ? 64 : 32;   // rows per wave
    constexpr int MI = WRR / 16;
    __shared__ bf16 SM[2][(BM + BN) * 64];       // linear (gload_lds dest), A then B
    const int m0 = blockIdx.y * BM, n0 = blockIdx.x * BN;
    const int tid = threadIdx.x;
    const int wave = tid >> 6, lane = tid & 63, lr = lane & 15, lhi = lane >> 4;
    const int wr = wave >> 1, wc = wave & 1;
    const int sr = lane >> 3, sc8 = (lane & 7) * 8;

    f32x4 acc[MI][4] = {};

    auto stage = [&](int buf, int k0) {
#pragma unroll
        for (int p = 0; p < CHUNKS; ++p) {
            const int rr = p * 32 + wave * 8 + sr;
            bf16* l = &SM[buf][0] + p * 2048 + wave * 512;   // wave-uniform base
            const bf16* g = (p < BM / 32)
                ? (A  + (size_t)(m0 + rr) * K + k0 + sc8)
                : (Bt + (size_t)(n0 + rr - BM) * K + k0 + sc8);
            gload_lds16(g, l);
        }
    };

    stage(0, 0);
    __syncthreads();
    int buf = 0;
    for (int k0 = 0; k0 < K; k0 += 64) {
        if (k0 + 64 < K) stage(buf ^ 1, k0 + 64);   // prefetch overlaps compute
#pragma unroll
        for (int kk = 0; kk < 2; ++kk) {
            bf16x8 af[MI], bfr[4];
#pragma unroll
            for (int i = 0; i < MI; ++i)
                af[i] = *(const bf16x8*)&SM[buf][(wr * WRR + i * 16 + lr) * 64 + kk * 32 + lhi * 8];
#pragma unroll
            for (int j = 0; j < 4; ++j)
                bfr[j] = *(const bf16x8*)&SM[buf][(BM + wc * 64 + j * 16 + lr) * 64 + kk * 32 + lhi * 8];
#pragma unroll
            for (int i = 0; i < MI; ++i)
#pragma unroll
                for (int j = 0; j < 4; ++j)
                    acc[i][j] = __builtin_amdgcn_mfma_f32_16x16x32_bf16(af[i], bfr[j], acc[i][j], 0, 0, 0);
        }
        __syncthreads();   // drains prefetch vmcnt + protects buf reuse
        buf ^= 1;
    }

#pragma unroll
    for (int i = 0; i < MI; ++i) {
#pragma unroll
        for (int j = 0; j < 4; ++j) {
            const int col = n0 + wc * 64 + j * 16 + lr;
            const int row0 = m0 + wr * WRR + i * 16 + lhi * 4;
            if (MODE == 0) {
                const float bv = bias1[col];
#pragma unroll
                for (int r = 0; r < 4; ++r) {
                    const size_t idx = (size_t)(row0 + r) * N + col;
                    float v = acc[i][j][r] + bv;
                    if (HAS_RES) v += res[idx] * resScale;
                    if (GELU_EPI) v = 0.5f * v * (1.0f + erff(v * 0.70710678118654752f));
                    v *= outScale;
                    if (OUT_BF16) ((bf16*)o1)[idx] = (bf16)v;
                    else          ((float*)o1)[idx] = v;
                }
            } else {
                const int sec = col >> 10, cl = col & 1023;
                const bool isV = (MODE == 1) ? (sec == 2) : (sec == 1);
                const float* bp = (MODE == 1) ? (sec == 0 ? bias1 : sec == 1 ? bias2 : bias3)
                                              : (sec == 0 ? bias1 : bias2);
                const float bv = bp[cl];
                if (!isV) {
                    bf16* dst = (MODE == 1) ? (sec == 0 ? (bf16*)o1 : (bf16*)o2) : (bf16*)o1;
                    const float sc = (MODE == 1 && sec == 0) ? outScale : 1.f;
#pragma unroll
                    for (int r = 0; r < 4; ++r)
                        dst[(size_t)(row0 + r) * H_DIM + cl] = (bf16)((acc[i][j][r] + bv) * sc);
                } else {
                    bf16* dst = (MODE == 1) ? (bf16*)o3 : (bf16*)o2;
                    const int S = 1 << slog2;
                    const int bI = row0 >> slog2, s0 = row0 & (S - 1);
                    const int hI = cl >> 6, dI = cl & 63;
                    bf16x4 ov;
#pragma unroll
                    for (int r = 0; r < 4; ++r) ov[r] = (bf16)(acc[i][j][r] + bv);
                    *(bf16x4*)(dst + ((size_t)((bI * NHEAD + hI) * HD + dI)) * S + s0) = ov;
                }
            }
        }
    }
}

// ---------------- flash attention v5: swapped QK^T, P fully in-register ----------------
// Per lane: one q (= lr) per qi-group. K-fragment rows are PERMUTED at LDS-read time so
// the QK^T output lands each lane with exactly the 32 k-slots its PV B-fragment needs:
//   krow(nf,lr) = (nf>>1)*32 + (lr>>2)*8 + (nf&1)*4 + (lr&3)
//   => lane holds P[k = kk*32 + lhi*8 + j][q = qi*16+lr], j=0..7 adjacent in (nf&1, r)
// P -> PV B-operand is 16 v_cvt_pk_bf16_f32 per qi: no LDS, no shuffles.
// Staging: T14 async split (issue next tile's global loads before compute, ds_write after).
__global__ __launch_bounds__(256) void attn_kernel(const bf16* __restrict__ Qb,
                                                   const bf16* __restrict__ Kb,
                                                   const bf16* __restrict__ Vt_g,
                                                   bf16* __restrict__ Ob,
                                                   int SQ, int SK) {
    __shared__ bf16 SMEM[128 * 64 + 64 * 128];   // Kl | Vl ; reused for O-transpose
    bf16* Kl = SMEM;
    bf16* Vl = SMEM + 128 * 64;
    const int b = blockIdx.x >> 4, h = blockIdx.x & 15;
    const int q0 = blockIdx.y * 128;
    const int tid = threadIdx.x, wave = tid >> 6, lane = tid & 63;
    const int lr = lane & 15, lhi = lane >> 4;
    const size_t bh = (size_t)blockIdx.x;

    // Q as MFMA-B fragments (col = lr = q, k-slots = lhi*8+j)
    bf16x8 qf[2][2];
#pragma unroll
    for (int qi = 0; qi < 2; ++qi) {
        const bf16* qp = Qb + ((size_t)b * SQ + q0 + wave * 32 + qi * 16 + lr) * H_DIM + h * HD;
        qf[qi][0] = *(const bf16x8*)(qp + lhi * 8);
        qf[qi][1] = *(const bf16x8*)(qp + 32 + lhi * 8);
    }

    // lane-constant LDS read swizzles (match the staging-write swizzle xor7(row)=(row&3)|((row>>3&1)<<2))
    const int kx = (((lr & 3) | (((lr >> 2) & 1) << 2)) << 3);   // K rows: bit3 = lr>>2 (permuted rows)
    const int vx = (((lr & 3) | (((lr >> 3) & 1) << 2)) << 3);   // V rows: d = df*16+lr -> bit3 = lr>>3
    int krow[8];
#pragma unroll
    for (int nf = 0; nf < 8; ++nf)
        krow[nf] = (nf >> 1) * 32 + (lr >> 2) * 8 + (nf & 1) * 4 + (lr & 3);

    // staging coords
    const int rK = tid >> 3, cK = (tid & 7) * 8;      // K: 32 rows x 64 per pass
    const int dV = tid >> 4, cV = (tid & 15) * 8;     // V: 16 rows x 128 per pass
    const int kxw = (((rK & 3) | (((rK >> 3) & 1) << 2)) << 3);
    const int vxw = (((dV & 3) | (((dV >> 3) & 1) << 2)) << 3);
    const bf16* Kg = Kb + (size_t)b * SK * H_DIM + h * HD;
    const bf16* Vg = Vt_g + bh * 64 * (size_t)SK;

    float mrun[2] = {-1e30f, -1e30f}, lrun[2] = {0.f, 0.f};
    f32x4 o[2][4] = {};
    bf16x8 gKA[4], gVA[4], gKB[4], gVB[4];

    auto LOADG = [&](bf16x8 (&gk)[4], bf16x8 (&gv)[4], int kb) {
#pragma unroll
        for (int p = 0; p < 4; ++p) {
            gk[p] = *(const bf16x8*)(Kg + (size_t)(kb + p * 32 + rK) * H_DIM + cK);
            gv[p] = *(const bf16x8*)(Vg + (size_t)(p * 16 + dV) * SK + kb + cV);
        }
    };
    auto STORES = [&](bf16x8 (&gk)[4], bf16x8 (&gv)[4]) {
#pragma unroll
        for (int p = 0; p < 4; ++p) {
            *(bf16x8*)&Kl[(p * 32 + rK) * 64 + (cK ^ kxw)] = gk[p];
            *(bf16x8*)&Vl[(p * 16 + dV) * 128 + (cV ^ vxw)] = gv[p];
        }
    };
    auto COMPUTE = [&]() {
        f32x4 s[2][8] = {};
#pragma unroll
        for (int nf = 0; nf < 8; ++nf) {
            const int base = krow[nf] * 64;
            bf16x8 kf0 = *(const bf16x8*)&Kl[base + ((lhi * 8) ^ kx)];
            bf16x8 kf1 = *(const bf16x8*)&Kl[base + ((32 + lhi * 8) ^ kx)];
            s[0][nf] = __builtin_amdgcn_mfma_f32_16x16x32_bf16(kf0, qf[0][0], s[0][nf], 0, 0, 0);
            s[0][nf] = __builtin_amdgcn_mfma_f32_16x16x32_bf16(kf1, qf[0][1], s[0][nf], 0, 0, 0);
            s[1][nf] = __builtin_amdgcn_mfma_f32_16x16x32_bf16(kf0, qf[1][0], s[1][nf], 0, 0, 0);
            s[1][nf] = __builtin_amdgcn_mfma_f32_16x16x32_bf16(kf1, qf[1][1], s[1][nf], 0, 0, 0);
        }
        unsigned pw[2][16];
#pragma unroll
        for (int qi = 0; qi < 2; ++qi) {
            float tm = s[qi][0][0];
#pragma unroll
            for (int nf = 0; nf < 8; ++nf)
#pragma unroll
                for (int r = 0; r < 4; ++r) tm = fmaxf(tm, s[qi][nf][r]);
            tm = fmaxf(tm, __shfl_xor(tm, 16));
            tm = fmaxf(tm, __shfl_xor(tm, 32));
            // defer-max (T13): skip O/l rescale while tile max within 2^8 of running max
            if (!__all(tm <= mrun[qi] + 8.f)) {
                float mn = fmaxf(mrun[qi], tm);
                float al = exp2f(mrun[qi] - mn);
                mrun[qi] = mn;
                lrun[qi] *= al;
#pragma unroll
                for (int df = 0; df < 4; ++df) o[qi][df] *= al;
            }
            float rs = 0.f;
#pragma unroll
            for (int nf = 0; nf < 8; ++nf) {
                float p0 = exp2f(s[qi][nf][0] - mrun[qi]);
                float p1 = exp2f(s[qi][nf][1] - mrun[qi]);
                float p2 = exp2f(s[qi][nf][2] - mrun[qi]);
                float p3 = exp2f(s[qi][nf][3] - mrun[qi]);
                rs += (p0 + p1) + (p2 + p3);
                pw[qi][nf * 2]     = cvtpk_bf16(p0, p1);
                pw[qi][nf * 2 + 1] = cvtpk_bf16(p2, p3);
            }
            rs += __shfl_xor(rs, 16);
            rs += __shfl_xor(rs, 32);
            lrun[qi] += rs;
        }
#pragma unroll
        for (int kk = 0; kk < 4; ++kk) {
            bf16x8 pb[2];
#pragma unroll
            for (int qi = 0; qi < 2; ++qi) {
                int4v w = { (int)pw[qi][kk * 4], (int)pw[qi][kk * 4 + 1],
                            (int)pw[qi][kk * 4 + 2], (int)pw[qi][kk * 4 + 3] };
                pb[qi] = __builtin_bit_cast(bf16x8, w);
            }
#pragma unroll
            for (int df = 0; df < 4; ++df) {
                bf16x8 vf = *(const bf16x8*)&Vl[(df * 16 + lr) * 128 + ((kk * 32 + lhi * 8) ^ vx)];
                o[0][df] = __builtin_amdgcn_mfma_f32_16x16x32_bf16(vf, pb[0], o[0][df], 0, 0, 0);
                o[1][df] = __builtin_amdgcn_mfma_f32_16x16x32_bf16(vf, pb[1], o[1][df], 0, 0, 0);
            }
        }
    };

    const int nt = SK >> 7;
    LOADG(gKA, gVA, 0);
    for (int t = 0; t < nt; t += 2) {
        __syncthreads();
        STORES(gKA, gVA);                       // vmcnt wait inserted by compiler
        if (t + 1 < nt) LOADG(gKB, gVB, (t + 1) << 7);   // in flight across compute
        __syncthreads();
        COMPUTE();
        if (t + 1 < nt) {
            __syncthreads();
            STORES(gKB, gVB);
            if (t + 2 < nt) LOADG(gKA, gVA, (t + 2) << 7);
            __syncthreads();
            COMPUTE();
        }
    }

    // epilogue: per-wave O^T -> O transpose through LDS (one-time), coalesced store
    __syncthreads();
    bf16* T = SMEM + wave * (32 * 72);          // stride-72 pad: bank-spread
#pragma unroll
    for (int qi = 0; qi < 2; ++qi) {
        const float inv = 1.0f / lrun[qi];
#pragma unroll
        for (int df = 0; df < 4; ++df)
#pragma unroll
            for (int r = 0; r < 4; ++r)
                T[(qi * 16 + lr) * 72 + df * 16 + lhi * 4 + r] = (bf16)(o[qi][df][r] * inv);
    }
#pragma unroll
    for (int pp = 0; pp < 4; ++pp) {
        const int r32 = pp * 8 + (lane >> 3), ch = (lane & 7) * 8;
        bf16x8 v = *(const bf16x8*)&T[r32 * 72 + ch];
        *(bf16x8*)(Ob + ((size_t)b * SQ + q0 + wave * 32 + r32) * H_DIM + h * HD + ch) = v;
    }
}

extern "C" void kernel_launch(void* const* d_in, const int* in_sizes, int n_in,
                              void* d_out, int out_size, void* d_ws, size_t ws_size,
                              hipStream_t stream) {
    const float* x    = (const float*)d_in[0];
    const float* img  = (const float*)d_in[1];
    const float* W_sq = (const float*)d_in[2];   const float* b_sq = (const float*)d_in[3];
    const float* W_sk = (const float*)d_in[4];   const float* b_sk = (const float*)d_in[5];
    const float* W_sv = (const float*)d_in[6];   const float* b_sv = (const float*)d_in[7];
    const float* W_so = (const float*)d_in[8];   const float* b_so = (const float*)d_in[9];
    const float* W_cq = (const float*)d_in[10];  const float* b_cq = (const float*)d_in[11];
    const float* W_ck = (const float*)d_in[12];  const float* b_ck = (const float*)d_in[13];
    const float* W_cv = (const float*)d_in[14];  const float* b_cv = (const float*)d_in[15];
    const float* W_co = (const float*)d_in[16];  const float* b_co = (const float*)d_in[17];
    const float* W_f1 = (const float*)d_in[18];  const float* b_f1 = (const float*)d_in[19];
    const float* W_f2 = (const float*)d_in[20];  const float* b_f2 = (const float*)d_in[21];
    const float* g1 = (const float*)d_in[22];    const float* bb1 = (const float*)d_in[23];
    const float* g2 = (const float*)d_in[24];    const float* bb2 = (const float*)d_in[25];
    const float* g3 = (const float*)d_in[26];    const float* bb3 = (const float*)d_in[27];

    char* ws = (char*)d_ws;
    const size_t MB = 1ull << 20;
    bf16* WT   = (bf16*)ws;
    bf16* w_sq = WT + 0 * (1u << 20);   // sq,sk,sv contiguous -> fused QKV weight [3072][1024]
    bf16* w_sk = WT + 1 * (1u << 20);
    bf16* w_sv = WT + 2 * (1u << 20);
    bf16* w_so = WT + 3 * (1u << 20);
    bf16* w_cq = WT + 4 * (1u << 20);
    bf16* w_ck = WT + 5 * (1u << 20);   // ck,cv contiguous -> fused KV weight [2048][1024]
    bf16* w_cv = WT + 6 * (1u << 20);
    bf16* w_co = WT + 7 * (1u << 20);
    bf16* w_f1 = WT + 8 * (1u << 20);   // [4096][1024]
    bf16* w_f2 = WT + 12 * (1u << 20);  // [1024][4096]
    float* XR  = (float*)(ws + 32 * MB);
    bf16* NX   = (bf16*)(ws + 48 * MB);
    bf16* Qb   = (bf16*)(ws + 56 * MB);
    bf16* Kb   = (bf16*)(ws + 64 * MB);
    bf16* Vt   = (bf16*)(ws + 72 * MB);  // [b][h][d][s]
    bf16* FF   = (bf16*)(ws + 56 * MB);  // reused after attention
    bf16* IMGB = (bf16*)(ws + 88 * MB);

    const dim3 blk(256);

    wconv_kernel<<<dim3(16, 16), blk, 0, stream>>>(W_sq, w_sq, 1024, 1024);
    wconv_kernel<<<dim3(16, 16), blk, 0, stream>>>(W_sk, w_sk, 1024, 1024);
    wconv_kernel<<<dim3(16, 16), blk, 0, stream>>>(W_sv, w_sv, 1024, 1024);
    wconv_kernel<<<dim3(16, 16), blk, 0, stream>>>(W_so, w_so, 1024, 1024);
    wconv_kernel<<<dim3(16, 16), blk, 0, stream>>>(W_cq, w_cq, 1024, 1024);
    wconv_kernel<<<dim3(16, 16), blk, 0, stream>>>(W_ck, w_ck, 1024, 1024);
    wconv_kernel<<<dim3(16, 16), blk, 0, stream>>>(W_cv, w_cv, 1024, 1024);
    wconv_kernel<<<dim3(16, 16), blk, 0, stream>>>(W_co, w_co, 1024, 1024);
    wconv_kernel<<<dim3(64, 16), blk, 0, stream>>>(W_f1, w_f1, 1024, 4096);
    wconv_kernel<<<dim3(16, 64), blk, 0, stream>>>(W_f2, w_f2, 4096, 1024);

    // ---- self attention ----
    ln_kernel<<<4096, blk, 0, stream>>>(x, 0.1f, g1, bb1, NX);
    gemm_kernel<128, 1, true, false, false><<<dim3(24, 32), blk, 0, stream>>>(
        NX, w_sq, b_sq, b_sk, b_sv, nullptr, Qb, Kb, Vt, 4096, 3072, 1024, 0.f, QSCL, 11);
    attn_kernel<<<dim3(32, 16), blk, 0, stream>>>(Qb, Kb, Vt, NX, 2048, 2048);
    gemm_kernel<64, 0, false, false, true><<<dim3(8, 64), blk, 0, stream>>>(
        NX, w_so, b_so, nullptr, nullptr, x, XR, nullptr, nullptr, 4096, 1024, 1024, 0.1f, 1.f, 0);

    // ---- cross attention ----
    ln_kernel<<<4096, blk, 0, stream>>>(XR, 1.f, g2, bb2, NX);
    gemm_kernel<64, 0, true, false, false><<<dim3(8, 64), blk, 0, stream>>>(
        NX, w_cq, b_cq, nullptr, nullptr, nullptr, Qb, nullptr, nullptr, 4096, 1024, 1024, 0.f, QSCL, 0);
    cvt_scale_kernel<<<dim3(512), blk, 0, stream>>>(img, IMGB, 0.1f, 131072);
    gemm_kernel<64, 2, true, false, false><<<dim3(16, 8), blk, 0, stream>>>(
        IMGB, w_ck, b_ck, b_cv, nullptr, nullptr, Kb, Vt, nullptr, 512, 2048, 1024, 0.f, 1.f, 8);
    attn_kernel<<<dim3(32, 16), blk, 0, stream>>>(Qb, Kb, Vt, NX, 2048, 256);
    gemm_kernel<64, 0, false, false, true><<<dim3(8, 64), blk, 0, stream>>>(
        NX, w_co, b_co, nullptr, nullptr, XR, XR, nullptr, nullptr, 4096, 1024, 1024, 1.f, 1.f, 0);

    // ---- feed forward ----
    ln_kernel<<<4096, blk, 0, stream>>>(XR, 1.f, g3, bb3, NX);
    gemm_kernel<128, 0, true, true, false><<<dim3(32, 32), blk, 0, stream>>>(
        NX, w_f1, b_f1, nullptr, nullptr, nullptr, FF, nullptr, nullptr, 4096, 4096, 1024, 0.f, 1.f, 0);
    gemm_kernel<64, 0, false, false, true><<<dim3(8, 64), blk, 0, stream>>>(
        FF, w_f2, b_f2, nullptr, nullptr, XR, d_out, nullptr, nullptr, 4096, 1024, 4096, 1.f, 10.f, 0);
}